// Round 13
// baseline (387.284 us; speedup 1.0000x reference)
//
#include <hip/hip_runtime.h>
#include <hip/hip_bf16.h>
#include <stdint.h>

// ---------- types ----------
typedef __attribute__((ext_vector_type(8)))  short bf16x8;
typedef __attribute__((ext_vector_type(4)))  float f32x4;
typedef __attribute__((ext_vector_type(4)))  float float4v;
typedef __attribute__((ext_vector_type(8)))  unsigned short u16x8;

#define MFMA16(a,b,c) __builtin_amdgcn_mfma_f32_16x16x32_bf16((a),(b),(c),0,0,0)

__device__ __forceinline__ unsigned short f2bf(float f) {
    unsigned int u = __builtin_bit_cast(unsigned int, f);
    u = (u + 0x7fffu + ((u >> 16) & 1u)) >> 16;
    return (unsigned short)u;
}

__device__ __forceinline__ void gload_lds16(const void* g, void* l) {
    __builtin_amdgcn_global_load_lds(
        (const __attribute__((address_space(1))) void*)g,
        (__attribute__((address_space(3))) void*)l, 16, 0, 0);
}

template<int N> __device__ __forceinline__ void waitvm() {}  // N<0: no wait
template<> __device__ __forceinline__ void waitvm<6>() { asm volatile("s_waitcnt vmcnt(6)" ::: "memory"); }
template<> __device__ __forceinline__ void waitvm<4>() { asm volatile("s_waitcnt vmcnt(4)" ::: "memory"); }
template<> __device__ __forceinline__ void waitvm<0>() { asm volatile("s_waitcnt vmcnt(0)" ::: "memory"); }

// ---------- fp32 -> bf16 convert: hs and vt in ONE launch ----------
__global__ void cvt_all(const float* __restrict__ hs, const float* __restrict__ vt,
                        unsigned short* __restrict__ hs_bf, unsigned short* __restrict__ vt_bf) {
    if (blockIdx.x < 2048) {
        long i = ((long)blockIdx.x * blockDim.x + threadIdx.x) * 8;
        const long stride = 2048L * 256 * 8;
        for (; i < 67108864L; i += stride) {
            float4v v0 = *(const float4v*)(hs + i);
            float4v v1 = *(const float4v*)(hs + i + 4);
            u16x8 o;
            o[0] = f2bf(v0[0]); o[1] = f2bf(v0[1]); o[2] = f2bf(v0[2]); o[3] = f2bf(v0[3]);
            o[4] = f2bf(v1[0]); o[5] = f2bf(v1[1]); o[6] = f2bf(v1[2]); o[7] = f2bf(v1[3]);
            *(u16x8*)(hs_bf + i) = o;
        }
    } else {
        long i = ((long)(blockIdx.x - 2048) * blockDim.x + threadIdx.x) * 8;
        const long stride = 512L * 256 * 8;
        for (; i < 8388608L; i += stride) {
            float4v v0 = *(const float4v*)(vt + i);
            float4v v1 = *(const float4v*)(vt + i + 4);
            u16x8 o;
            o[0] = f2bf(v0[0]); o[1] = f2bf(v0[1]); o[2] = f2bf(v0[2]); o[3] = f2bf(v0[3]);
            o[4] = f2bf(v1[0]); o[5] = f2bf(v1[1]); o[6] = f2bf(v1[2]); o[7] = f2bf(v1[3]);
            *(u16x8*)(vt_bf + i) = o;
        }
    }
}

// ---------- Fused GEMM: z = H @ VT^T (round-12 single-barrier 8-phase, verified),
// then grouped up-projection out = z @ U[g]^T fused in the epilogue. ----------
// Main loop IDENTICAL to round 12 (221 us, 0 conflicts, absmax 0.25).
// Epilogue design (fixing round-3's two measured sinks):
//  - out = MFMA(A = z-frag, B = U-frag): C/D col = d, row = m -> coalesced
//    64B-per-16-lane stores (gemm2's pattern), NOT the 16B-scattered stores
//    that inflated round-3's hbm_bytes to 826 MB.
//  - z dumped to per-wave-private LDS zw[m][r] (wid*16KB; reuses main LDS).
//    Dump/read index math verified in round 3 (passed, absmax 0.25).
//  - No barrier needed after the K-loop: passing BARX(P8) implies every wave
//    drained its last LDS reads (P6-tails drained at P7-entry lgkm0, P7/P8
//    phases read registers only).
//  - U[g] read from global as B-operand frags; XCD-local (g>>2 == bid&7) so
//    each XCD's L2 holds only 4 groups = 128 KB.

#define STAGE_A(nA_, k0n, h, l) \
    gload_lds16(pA + ((l)*128 + (h)*64) * 4096L + (k0n), (nA_) + dA0 + ((l)*128 + (h)*64) * 64)
#define STAGE_B(nB_, k0n, h, l) \
    gload_lds16(pB + ((l)*128 + (h)*32) * 4096L + (k0n), (nB_) + dB0 + ((l)*128 + (h)*32) * 64)

#define LDA(dst_, sA_, QM) do { _Pragma("unroll") for (int mi = 0; mi < 4; ++mi) { \
    dst_[mi][0] = *(const bf16x8*)((sA_) + ((wr*128 + (QM)*64 + mi*16 + lan15) << 6) + g0); \
    dst_[mi][1] = *(const bf16x8*)((sA_) + ((wr*128 + (QM)*64 + mi*16 + lan15) << 6) + (g0 ^ 32)); } } while (0)
#define LDB(dst_, sB_, QN) do { _Pragma("unroll") for (int ni = 0; ni < 2; ++ni) { \
    dst_[ni][0] = *(const bf16x8*)((sB_) + ((wc*64 + (QN)*32 + ni*16 + lan15) << 6) + g0); \
    dst_[ni][1] = *(const bf16x8*)((sB_) + ((wc*64 + (QN)*32 + ni*16 + lan15) << 6) + (g0 ^ 32)); } } while (0)

#define DOMFMA(QM, QN, aset_, bset_) do { __builtin_amdgcn_s_setprio(1); \
    _Pragma("unroll") for (int mi = 0; mi < 4; ++mi) \
      _Pragma("unroll") for (int ni = 0; ni < 2; ++ni) { \
        acc[(QM)*4+mi][(QN)*2+ni] = MFMA16(aset_[mi][0], bset_[ni][0], acc[(QM)*4+mi][(QN)*2+ni]); \
        acc[(QM)*4+mi][(QN)*2+ni] = MFMA16(aset_[mi][1], bset_[ni][1], acc[(QM)*4+mi][(QN)*2+ni]); } \
    __builtin_amdgcn_s_setprio(0); } while (0)

#define BARX() do { __builtin_amdgcn_s_barrier(); \
    asm volatile("s_waitcnt lgkmcnt(0)" ::: "memory"); \
    __builtin_amdgcn_sched_barrier(0); } while (0)
#define SB() __builtin_amdgcn_sched_barrier(0)

#define ITER8(K1, K2, K3, S2, S3, T8, V3, V7) do { \
  /*P1*/ STAGE_A(bA1, K1, 1, 0); STAGE_A(bA1, K1, 1, 1); \
         BARX(); DOMFMA(0, 0, aE, b0); LDB(b1, bB0, 1); SB(); \
  /*P2*/ BARX(); DOMFMA(0, 1, aE, b1); LDA(aO, bA0, 1); SB(); \
  /*P3*/ if (S2) { STAGE_A(bA0, K2, 0, 0); STAGE_A(bA0, K2, 0, 1); \
                   STAGE_B(bB0, K2, 0, 0); STAGE_B(bB0, K2, 0, 1); } \
         BARX(); DOMFMA(1, 1, aO, b1); waitvm<V3>(); SB(); \
  /*P4*/ if (S2) { STAGE_B(bB0, K2, 1, 0); STAGE_B(bB0, K2, 1, 1); } \
         BARX(); DOMFMA(1, 0, aO, b0); LDA(aE, bA1, 0); LDB(b0, bB1, 0); SB(); \
  /*P5*/ if (S2) { STAGE_A(bA0, K2, 1, 0); STAGE_A(bA0, K2, 1, 1); } \
         BARX(); DOMFMA(0, 0, aE, b0); LDB(b1, bB1, 1); SB(); \
  /*P6*/ BARX(); DOMFMA(0, 1, aE, b1); LDA(aO, bA1, 1); SB(); \
  /*P7*/ if (S3) { STAGE_A(bA1, K3, 0, 0); STAGE_A(bA1, K3, 0, 1); \
                   STAGE_B(bB1, K3, 0, 0); STAGE_B(bB1, K3, 0, 1); } \
         BARX(); DOMFMA(1, 1, aO, b1); waitvm<V7>(); SB(); \
  /*P8*/ if (S3) { STAGE_B(bB1, K3, 1, 0); STAGE_B(bB1, K3, 1, 1); } \
         BARX(); DOMFMA(1, 0, aO, b0); \
         if (T8) { LDA(aE, bA0, 0); LDB(b0, bB0, 0); } SB(); \
} while (0)

__global__ __launch_bounds__(512, 2) void gemm_fused(const unsigned short* __restrict__ A,  // [16384][4096]
                                                     const unsigned short* __restrict__ B,  // [2048][4096]
                                                     const float* __restrict__ Uw,          // [32][128][64]
                                                     float* __restrict__ out) {             // [16384][4096]
    __shared__ __align__(16) unsigned short lds[65536];   // 128 KiB

    const int tid   = threadIdx.x;
    const int lane  = tid & 63;
    const int wid   = tid >> 6;
    const int wr    = wid >> 2;          // 0..1
    const int wc    = wid & 3;           // 0..3
    const int lan15 = lane & 15;
    const int q     = lane >> 4;         // 0..3
    const int g0    = (((lane >> 4) ^ (lane & 7)) << 3);

    const int  bid = blockIdx.x;
    const long m0  = (long)(bid >> 3) * 256;
    const long n0  = (long)(bid & 7) * 256;

    const int q8    = tid >> 3;
    const int granA = (((tid & 7) ^ (q8 & 7)) << 3);
    const unsigned short* pA = A + (m0 + q8) * 4096L + granA;
    const int rB0   = (q8 & 31) + ((q8 >> 5) << 6);
    const unsigned short* pB = B + (n0 + rB0) * 4096L + granA;
    const int dA0   = (wid * 8) * 64;
    const int dB0   = ((wid & 3) * 8 + ((wid >> 2) << 6)) * 64;

    f32x4 acc[8][4] = {};
    bf16x8 aE[4][2], aO[4][2], b0[2][2], b1[2][2];

    unsigned short* bA0 = lds;
    unsigned short* bB0 = lds + 16384;
    unsigned short* bA1 = lds + 32768;
    unsigned short* bB1 = lds + 49152;

    // ---- prologue (round-12 verified) ----
    STAGE_A(bA0, 0, 0, 0);  STAGE_A(bA0, 0, 0, 1);
    STAGE_B(bB0, 0, 0, 0);  STAGE_B(bB0, 0, 0, 1);
    STAGE_B(bB0, 0, 1, 0);  STAGE_B(bB0, 0, 1, 1);
    STAGE_A(bA0, 0, 1, 0);  STAGE_A(bA0, 0, 1, 1);
    STAGE_A(bA1, 64, 0, 0); STAGE_A(bA1, 64, 0, 1);
    STAGE_B(bB1, 64, 0, 0); STAGE_B(bB1, 64, 0, 1);
    STAGE_B(bB1, 64, 1, 0); STAGE_B(bB1, 64, 1, 1);
    waitvm<6>();
    __builtin_amdgcn_s_barrier();
    __builtin_amdgcn_sched_barrier(0);
    LDA(aE, bA0, 0); LDB(b0, bB0, 0);
    SB();

    // ---- main loop: iters 0..30 ----
    for (int i = 0; i < 31; ++i) {
        ITER8((2 * i + 1) * 64, (2 * i + 2) * 64, (2 * i + 3) * 64,
              true, true, true, 4, 4);
    }
    // ---- final iter (tiles 62,63) ----
    ITER8(63 * 64, 0, 0, false, false, false, 0, -1);

    // ==== fused grouped up-projection epilogue ====
    // out[m, g*128+d] = sum_r z[m, g*64+r] * U[g][d][r], g = (bid&7)*4 + wc.
    {
        unsigned short* zw = lds + wid * 8192;   // per-wave private 16 KB

        // 1) dump acc -> zw[m][r] bf16, granule-swizzled (round-3 verified math)
        #pragma unroll
        for (int mi = 0; mi < 8; ++mi)
            #pragma unroll
            for (int ni = 0; ni < 4; ++ni)
                #pragma unroll
                for (int j = 0; j < 4; ++j) {
                    const int ml = mi * 16 + q * 4 + j;
                    const int rr = ni * 16 + lan15;
                    zw[ml * 64 + ((((rr >> 3)) ^ (ml & 7)) << 3) + (rr & 7)] = f2bf(acc[mi][ni][j]);
                }
        asm volatile("s_waitcnt lgkmcnt(0)" ::: "memory");
        __builtin_amdgcn_sched_barrier(0);

        // 2) per d-fragment: U B-frag from global (row d = nf*16+lan15, k = rk*32+q*8),
        //    MFMA(A=z-frag, B=U-frag) -> C col = d (coalesced stores), row = m.
        const int g_blk = (bid & 7) * 4 + wc;
        const float* ug = Uw + (long)g_blk * 8192;
        const long orow0 = m0 + wr * 128;
        const long ocol0 = (long)g_blk * 128;
        #pragma unroll
        for (int nf = 0; nf < 8; ++nf) {
            bf16x8 ub[2];
            #pragma unroll
            for (int rk = 0; rk < 2; ++rk) {
                const float* up = ug + (nf * 16 + lan15) * 64 + rk * 32 + q * 8;
                float4v u0 = *(const float4v*)up;
                float4v u1 = *(const float4v*)(up + 4);
                u16x8 t;
                t[0] = f2bf(u0[0]); t[1] = f2bf(u0[1]); t[2] = f2bf(u0[2]); t[3] = f2bf(u0[3]);
                t[4] = f2bf(u1[0]); t[5] = f2bf(u1[1]); t[6] = f2bf(u1[2]); t[7] = f2bf(u1[3]);
                ub[rk] = __builtin_bit_cast(bf16x8, t);
            }
            #pragma unroll
            for (int mf = 0; mf < 8; ++mf) {
                f32x4 o = {};
                #pragma unroll
                for (int rk = 0; rk < 2; ++rk) {
                    const int ml = mf * 16 + lan15;
                    const int gr = (rk * 4 + q) ^ (ml & 7);
                    const bf16x8 za = *(const bf16x8*)&zw[ml * 64 + gr * 8];
                    o = MFMA16(za, ub[rk], o);
                }
                const long mrow = orow0 + mf * 16 + q * 4;
                const long ocol = ocol0 + nf * 16 + lan15;
                #pragma unroll
                for (int j = 0; j < 4; ++j)
                    out[(mrow + j) * 4096L + ocol] = o[j];
            }
        }
    }
}

// ---------- launch ----------
extern "C" void kernel_launch(void* const* d_in, const int* in_sizes, int n_in,
                              void* d_out, int out_size, void* d_ws, size_t ws_size,
                              hipStream_t stream) {
    const float* hs = (const float*)d_in[0];   // [4,4096,4096] fp32
    const float* vt = (const float*)d_in[1];   // [2048,4096]   fp32
    const float* uw = (const float*)d_in[2];   // [32,128,64]   fp32
    float* out = (float*)d_out;

    unsigned short* hs_bf = (unsigned short*)d_ws;            // 67108864 bf16
    unsigned short* vt_bf = hs_bf + 67108864L;                //  8388608 bf16

    // one conversion launch: blocks 0..2047 -> hs, 2048..2559 -> vt
    cvt_all<<<2560, 256, 0, stream>>>(hs, vt, hs_bf, vt_bf);

    // fused GEMM + grouped up-projection: 64 x 8 = 512 blocks, 512 threads
    gemm_fused<<<512, 512, 0, stream>>>(hs_bf, vt_bf, uw, out);
}

// Round 14
// 359.538 us; speedup vs baseline: 1.0772x; 1.0772x over previous
//
#include <hip/hip_runtime.h>
#include <hip/hip_bf16.h>
#include <stdint.h>

// ---------- types ----------
typedef __attribute__((ext_vector_type(8)))  short bf16x8;
typedef __attribute__((ext_vector_type(4)))  float f32x4;
typedef __attribute__((ext_vector_type(4)))  float float4v;
typedef __attribute__((ext_vector_type(8)))  unsigned short u16x8;

#define MFMA16(a,b,c) __builtin_amdgcn_mfma_f32_16x16x32_bf16((a),(b),(c),0,0,0)

__device__ __forceinline__ unsigned short f2bf(float f) {
    unsigned int u = __builtin_bit_cast(unsigned int, f);
    u = (u + 0x7fffu + ((u >> 16) & 1u)) >> 16;
    return (unsigned short)u;
}

__device__ __forceinline__ void gload_lds16(const void* g, void* l) {
    __builtin_amdgcn_global_load_lds(
        (const __attribute__((address_space(1))) void*)g,
        (__attribute__((address_space(3))) void*)l, 16, 0, 0);
}

template<int N> __device__ __forceinline__ void waitvm() {}  // N<0: no wait
template<> __device__ __forceinline__ void waitvm<6>() { asm volatile("s_waitcnt vmcnt(6)" ::: "memory"); }
template<> __device__ __forceinline__ void waitvm<4>() { asm volatile("s_waitcnt vmcnt(4)" ::: "memory"); }
template<> __device__ __forceinline__ void waitvm<0>() { asm volatile("s_waitcnt vmcnt(0)" ::: "memory"); }

// ---------- fp32 -> bf16 convert: hs and vt in ONE launch (BW floor ~69 us) ----------
__global__ void cvt_all(const float* __restrict__ hs, const float* __restrict__ vt,
                        unsigned short* __restrict__ hs_bf, unsigned short* __restrict__ vt_bf) {
    if (blockIdx.x < 2048) {
        long i = ((long)blockIdx.x * blockDim.x + threadIdx.x) * 8;
        const long stride = 2048L * 256 * 8;
        for (; i < 67108864L; i += stride) {
            float4v v0 = *(const float4v*)(hs + i);
            float4v v1 = *(const float4v*)(hs + i + 4);
            u16x8 o;
            o[0] = f2bf(v0[0]); o[1] = f2bf(v0[1]); o[2] = f2bf(v0[2]); o[3] = f2bf(v0[3]);
            o[4] = f2bf(v1[0]); o[5] = f2bf(v1[1]); o[6] = f2bf(v1[2]); o[7] = f2bf(v1[3]);
            *(u16x8*)(hs_bf + i) = o;
        }
    } else {
        long i = ((long)(blockIdx.x - 2048) * blockDim.x + threadIdx.x) * 8;
        const long stride = 512L * 256 * 8;
        for (; i < 8388608L; i += stride) {
            float4v v0 = *(const float4v*)(vt + i);
            float4v v1 = *(const float4v*)(vt + i + 4);
            u16x8 o;
            o[0] = f2bf(v0[0]); o[1] = f2bf(v0[1]); o[2] = f2bf(v0[2]); o[3] = f2bf(v0[3]);
            o[4] = f2bf(v1[0]); o[5] = f2bf(v1[1]); o[6] = f2bf(v1[2]); o[7] = f2bf(v1[3]);
            *(u16x8*)(vt_bf + i) = o;
        }
    }
}

// ---------- GEMM1: z = H(bf16) @ VT(bf16)^T, 256x256 tile, 16x16x32 MFMA ----------
// Round-12 verified SINGLE-BARRIER 8-phase schedule (221 us, MfmaUtil 56%,
// 0 bank conflicts, absmax 0.25). Safety model: a wave issuing stage(p) has
// passed BAR(p-1) => all waves arrived BAR(p-1) => all executed lgkm(0) after
// BAR(p-2) => all drained tail-reads from phases <= p-3. All restage gaps = 3.
//
// Stage map (iter i computes u=2i, v=2i+1; stages u+2 -> bufs0, v+2 -> bufs1):
//   P1: Ah1(v)->A1.h1 [2]     P3: Ah0(u+2)->A0.h0, Bh0(u+2)->B0.h0 [4]
//   P4: Bh1(u+2)->B0.h1 [2]   P5: Ah1(u+2)->A0.h1 [2]
//   P7: Ah0(v+2)->A1.h0, Bh0(v+2)->B1.h0 [4]   P8: Bh1(v+2)->B1.h1 [2]
// Waits: W3 = vmcnt(4) end-P3 (retires thru P1(i)); W7 = vmcnt(4) end-P7
// (retires thru P5(i)). All ds_reads are TAILS (after DOMFMA):
//   P1: b1<-B0.h1   P2: aO<-A0.h1   P4: aE<-A1.h0, b0<-B1.h0
//   P5: b1<-B1.h1   P6: aO<-A1.h1   P8: aE<-A0.h0, b0<-B0.h0
// Every tail sits after its covering wait's barrier (cross-wave visibility);
// every stage->wait spans >= 2 phases (HBM latency).

#define STAGE_A(nA_, k0n, h, l) \
    gload_lds16(pA + ((l)*128 + (h)*64) * 4096L + (k0n), (nA_) + dA0 + ((l)*128 + (h)*64) * 64)
#define STAGE_B(nB_, k0n, h, l) \
    gload_lds16(pB + ((l)*128 + (h)*32) * 4096L + (k0n), (nB_) + dB0 + ((l)*128 + (h)*32) * 64)

#define LDA(dst_, sA_, QM) do { _Pragma("unroll") for (int mi = 0; mi < 4; ++mi) { \
    dst_[mi][0] = *(const bf16x8*)((sA_) + ((wr*128 + (QM)*64 + mi*16 + lan15) << 6) + g0); \
    dst_[mi][1] = *(const bf16x8*)((sA_) + ((wr*128 + (QM)*64 + mi*16 + lan15) << 6) + (g0 ^ 32)); } } while (0)
#define LDB(dst_, sB_, QN) do { _Pragma("unroll") for (int ni = 0; ni < 2; ++ni) { \
    dst_[ni][0] = *(const bf16x8*)((sB_) + ((wc*64 + (QN)*32 + ni*16 + lan15) << 6) + g0); \
    dst_[ni][1] = *(const bf16x8*)((sB_) + ((wc*64 + (QN)*32 + ni*16 + lan15) << 6) + (g0 ^ 32)); } } while (0)

#define DOMFMA(QM, QN, aset_, bset_) do { __builtin_amdgcn_s_setprio(1); \
    _Pragma("unroll") for (int mi = 0; mi < 4; ++mi) \
      _Pragma("unroll") for (int ni = 0; ni < 2; ++ni) { \
        acc[(QM)*4+mi][(QN)*2+ni] = MFMA16(aset_[mi][0], bset_[ni][0], acc[(QM)*4+mi][(QN)*2+ni]); \
        acc[(QM)*4+mi][(QN)*2+ni] = MFMA16(aset_[mi][1], bset_[ni][1], acc[(QM)*4+mi][(QN)*2+ni]); } \
    __builtin_amdgcn_s_setprio(0); } while (0)

#define BARX() do { __builtin_amdgcn_s_barrier(); \
    asm volatile("s_waitcnt lgkmcnt(0)" ::: "memory"); \
    __builtin_amdgcn_sched_barrier(0); } while (0)
#define SB() __builtin_amdgcn_sched_barrier(0)

#define ITER8(K1, K2, K3, S2, S3, T8, V3, V7) do { \
  /*P1*/ STAGE_A(bA1, K1, 1, 0); STAGE_A(bA1, K1, 1, 1); \
         BARX(); DOMFMA(0, 0, aE, b0); LDB(b1, bB0, 1); SB(); \
  /*P2*/ BARX(); DOMFMA(0, 1, aE, b1); LDA(aO, bA0, 1); SB(); \
  /*P3*/ if (S2) { STAGE_A(bA0, K2, 0, 0); STAGE_A(bA0, K2, 0, 1); \
                   STAGE_B(bB0, K2, 0, 0); STAGE_B(bB0, K2, 0, 1); } \
         BARX(); DOMFMA(1, 1, aO, b1); waitvm<V3>(); SB(); \
  /*P4*/ if (S2) { STAGE_B(bB0, K2, 1, 0); STAGE_B(bB0, K2, 1, 1); } \
         BARX(); DOMFMA(1, 0, aO, b0); LDA(aE, bA1, 0); LDB(b0, bB1, 0); SB(); \
  /*P5*/ if (S2) { STAGE_A(bA0, K2, 1, 0); STAGE_A(bA0, K2, 1, 1); } \
         BARX(); DOMFMA(0, 0, aE, b0); LDB(b1, bB1, 1); SB(); \
  /*P6*/ BARX(); DOMFMA(0, 1, aE, b1); LDA(aO, bA1, 1); SB(); \
  /*P7*/ if (S3) { STAGE_A(bA1, K3, 0, 0); STAGE_A(bA1, K3, 0, 1); \
                   STAGE_B(bB1, K3, 0, 0); STAGE_B(bB1, K3, 0, 1); } \
         BARX(); DOMFMA(1, 1, aO, b1); waitvm<V7>(); SB(); \
  /*P8*/ if (S3) { STAGE_B(bB1, K3, 1, 0); STAGE_B(bB1, K3, 1, 1); } \
         BARX(); DOMFMA(1, 0, aO, b0); \
         if (T8) { LDA(aE, bA0, 0); LDB(b0, bB0, 0); } SB(); \
} while (0)

__global__ __launch_bounds__(512, 2) void gemm1_8ph(const unsigned short* __restrict__ A,  // [16384][4096]
                                                    const unsigned short* __restrict__ B,  // [2048][4096]
                                                    unsigned short* __restrict__ Z) {      // [16384][2048]
    __shared__ __align__(16) unsigned short lds[65536];   // 128 KiB

    const int tid   = threadIdx.x;
    const int lane  = tid & 63;
    const int wid   = tid >> 6;
    const int wr    = wid >> 2;          // 0..1
    const int wc    = wid & 3;           // 0..3
    const int lan15 = lane & 15;
    const int g0    = (((lane >> 4) ^ (lane & 7)) << 3);

    const int  bid = blockIdx.x;
    const long m0  = (long)(bid >> 3) * 256;
    const long n0  = (long)(bid & 7) * 256;

    const int q8    = tid >> 3;
    const int granA = (((tid & 7) ^ (q8 & 7)) << 3);
    const unsigned short* pA = A + (m0 + q8) * 4096L + granA;
    const int rB0   = (q8 & 31) + ((q8 >> 5) << 6);
    const unsigned short* pB = B + (n0 + rB0) * 4096L + granA;
    const int dA0   = (wid * 8) * 64;
    const int dB0   = ((wid & 3) * 8 + ((wid >> 2) << 6)) * 64;

    f32x4 acc[8][4] = {};
    bf16x8 aE[4][2], aO[4][2], b0[2][2], b1[2][2];

    unsigned short* bA0 = lds;
    unsigned short* bB0 = lds + 16384;
    unsigned short* bA1 = lds + 32768;
    unsigned short* bB1 = lds + 49152;

    // ---- prologue ----
    STAGE_A(bA0, 0, 0, 0);  STAGE_A(bA0, 0, 0, 1);
    STAGE_B(bB0, 0, 0, 0);  STAGE_B(bB0, 0, 0, 1);
    STAGE_B(bB0, 0, 1, 0);  STAGE_B(bB0, 0, 1, 1);
    STAGE_A(bA0, 0, 1, 0);  STAGE_A(bA0, 0, 1, 1);
    STAGE_A(bA1, 64, 0, 0); STAGE_A(bA1, 64, 0, 1);
    STAGE_B(bB1, 64, 0, 0); STAGE_B(bB1, 64, 0, 1);
    STAGE_B(bB1, 64, 1, 0); STAGE_B(bB1, 64, 1, 1);
    waitvm<6>();            // retires t0's 8 issues in every wave
    __builtin_amdgcn_s_barrier();       // visibility for all waves
    __builtin_amdgcn_sched_barrier(0);
    LDA(aE, bA0, 0); LDB(b0, bB0, 0);   // prologue tail (drains at P1's BARX)
    SB();

    // ---- main loop: iters 0..30 (tiles 0..61 computed, 2..63 staged) ----
    for (int i = 0; i < 31; ++i) {
        ITER8((2 * i + 1) * 64, (2 * i + 2) * 64, (2 * i + 3) * 64,
              true, true, true, 4, 4);
    }
    // ---- final iter (tiles 62,63): stage only P1's Ah1(63); V3 drains ----
    ITER8(63 * 64, 0, 0, false, false, false, 0, -1);

    // ---- epilogue: z bf16 store; C/D col = lane&15 (n), row = (lane>>4)*4+j ----
    const int rq = (lane >> 4) << 2;
    #pragma unroll
    for (int mi = 0; mi < 8; ++mi) {
        #pragma unroll
        for (int ni = 0; ni < 4; ++ni) {
            const long mb  = m0 + wr * 128 + mi * 16 + rq;
            const long nb2 = n0 + wc * 64 + ni * 16 + lan15;
            #pragma unroll
            for (int j = 0; j < 4; ++j)
                Z[(mb + j) * 2048L + nb2] = f2bf(acc[mi][ni][j]);
        }
    }
}

// ---------- GEMM2: grouped up-projection (write-BW floor ~54 us) ----------
#define U_PAD 80

__global__ __launch_bounds__(256) void gemm2(const unsigned short* __restrict__ Z,  // [16384][2048] bf16
                                             const float* __restrict__ U,           // [32][128][64] f32
                                             float* __restrict__ out) {             // [16384][4096] f32
    __shared__ __align__(16) unsigned short lU[128 * U_PAD];

    const int tid  = threadIdx.x;
    const int lane = tid & 63;
    const int wid  = tid >> 6;
    const int g    = blockIdx.x & 31;
    const long m0  = (long)(blockIdx.x >> 5) * 64;

    const float* ug = U + (long)g * (128 * 64);
    for (int i = tid; i < (128 * 64) / 4; i += 256) {
        const int r = i >> 4;
        const int c = (i << 2) & 63;
        float4v v = *(const float4v*)(ug + i * 4);
        unsigned short* d = &lU[r * U_PAD + c];
        d[0] = f2bf(v[0]); d[1] = f2bf(v[1]); d[2] = f2bf(v[2]); d[3] = f2bf(v[3]);
    }
    __syncthreads();

    const long mrow = m0 + wid * 16 + (lane & 15);
    const unsigned short* zrow = Z + mrow * 2048L + g * 64 + ((lane >> 4) << 3);
    const bf16x8 a0 = *(const bf16x8*)(zrow);
    const bf16x8 a1 = *(const bf16x8*)(zrow + 32);

    f32x4 acc[8] = {};
    const int blds = (lane & 15);
    const int kofs = (lane >> 4) << 3;
    #pragma unroll
    for (int ni = 0; ni < 8; ++ni) {
        const bf16x8 c0 = *(const bf16x8*)&lU[(ni * 16 + blds) * U_PAD + kofs];
        const bf16x8 c1 = *(const bf16x8*)&lU[(ni * 16 + blds) * U_PAD + 32 + kofs];
        acc[ni] = MFMA16(a0, c0, acc[ni]);
        acc[ni] = MFMA16(a1, c1, acc[ni]);
    }

    const long mb = m0 + wid * 16 + ((lane >> 4) << 2);
    const long cb = (long)g * 128 + (lane & 15);
    #pragma unroll
    for (int ni = 0; ni < 8; ++ni)
        #pragma unroll
        for (int j = 0; j < 4; ++j)
            out[(mb + j) * 4096L + cb + ni * 16] = acc[ni][j];
}

// ---------- launch ----------
extern "C" void kernel_launch(void* const* d_in, const int* in_sizes, int n_in,
                              void* d_out, int out_size, void* d_ws, size_t ws_size,
                              hipStream_t stream) {
    const float* hs = (const float*)d_in[0];   // [4,4096,4096] fp32
    const float* vt = (const float*)d_in[1];   // [2048,4096]   fp32
    const float* uw = (const float*)d_in[2];   // [32,128,64]   fp32
    float* out = (float*)d_out;

    unsigned short* hs_bf = (unsigned short*)d_ws;            // 67108864 bf16
    unsigned short* vt_bf = hs_bf + 67108864L;                //  8388608 bf16
    unsigned short* z_bf  = vt_bf + 8388608L;                 // 33554432 bf16

    // one conversion launch: blocks 0..2047 -> hs, 2048..2559 -> vt
    cvt_all<<<2560, 256, 0, stream>>>(hs, vt, hs_bf, vt_bf);

    // GEMM1: (16384/256) x (2048/256) = 64 x 8 = 512 blocks, 512 threads
    gemm1_8ph<<<512, 512, 0, stream>>>(hs_bf, vt_bf, z_bf);

    // GEMM2: (16384/64) x 32 groups = 8192 blocks
    gemm2<<<8192, 256, 0, stream>>>(z_bf, uw, out);
}